// Round 7
// baseline (4599.702 us; speedup 1.0000x reference)
//
#include <hip/hip_runtime.h>
#include <stdint.h>

#define D 1024

typedef unsigned long long u64;
typedef unsigned int u32;

// ---------- monotonic float<->uint mapping for atomic max ----------
__device__ __forceinline__ u32 enc_f(float f) {
    u32 b = __float_as_uint(f);
    return (b & 0x80000000u) ? ~b : (b | 0x80000000u);
}
__device__ __forceinline__ float dec_f(u32 u) {
    u32 b = (u & 0x80000000u) ? (u ^ 0x80000000u) : ~u;
    return __uint_as_float(b);
}

// ---------- kernel A: max(X), max|X| ----------
__global__ void k_maxred(const float* __restrict__ X, u32* scal) {
    float mx = -INFINITY, ma = 0.f;
    int stride = gridDim.x * blockDim.x;
    for (int i = blockIdx.x * blockDim.x + threadIdx.x; i < D * D; i += stride) {
        float v = X[i];
        mx = fmaxf(mx, v);
        ma = fmaxf(ma, fabsf(v));
    }
    for (int o = 32; o; o >>= 1) {
        mx = fmaxf(mx, __shfl_xor(mx, o));
        ma = fmaxf(ma, __shfl_xor(ma, o));
    }
    if ((threadIdx.x & 63) == 0) {
        atomicMax(&scal[0], enc_f(mx));  // max_sim
        atomicMax(&scal[1], enc_f(ma));  // max|X|
    }
}

// ---------- kernel B: init dist (f32) and Wsym (f32, read-only afterwards) ----------
__global__ void k_init(const float* __restrict__ X, const float* __restrict__ W,
                       float* __restrict__ dist, float* __restrict__ wsym,
                       const u32* __restrict__ scal) {
    int idx = blockIdx.x * blockDim.x + threadIdx.x;
    if (idx >= D * D) return;
    float max_sim = dec_f(scal[0]);
    float MAXD = __fmul_rn(dec_f(scal[1]), 1000.0f);
    int i = idx >> 10, j = idx & (D - 1);
    float x = X[idx];
    // X is bitwise symmetric (0.5*(A+A^T)), so this matches max_sim - X[min][max]
    dist[idx] = (i == j) ? MAXD : __fsub_rn(max_sim, x);
    wsym[idx] = (i == j) ? 0.0f : (W[idx] + W[j * D + i]);  // one addend is exactly 0
}

// ---------- kernel B2: initial per-row (min,argmin) over upper triangle ----------
__global__ void k_rowmin(const float* __restrict__ dist, float* __restrict__ values_g,
                         int* __restrict__ indices_g, const u32* __restrict__ scal) {
    int r = blockIdx.x;
    int lane = threadIdx.x;  // 64 threads = 1 wave
    float MAXD = __fmul_rn(dec_f(scal[1]), 1000.0f);
    u64 best = ((u64)__float_as_uint(MAXD) << 32);  // (MAXD, idx 0) like jnp.argmin on all-MAXD row
    const float* row = dist + (size_t)r * D;
    for (int j = lane; j < D; j += 64) {
        if (j > r) {
            u64 k = ((u64)__float_as_uint(row[j]) << 32) | (u32)j;
            if (k < best) best = k;
        }
    }
    for (int o = 32; o; o >>= 1) {
        u64 k2 = __shfl_xor(best, o);
        if (k2 < best) best = k2;
    }
    if (lane == 0) {
        values_g[r] = __uint_as_float((u32)(best >> 32));
        indices_g[r] = (int)(best & 0xffffffffu);
    }
}

// ---------- kernel C: persistent single-block HAC loop, 2 barriers/iter ----------
// No cross matrix: cross(A,B) is summed directly from read-only Wsym over the
// member lists of the two merging clusters (total pairs over the whole run =
// D(D-1)/2). dist (4 MB) is the only writable matrix -> fits one XCD L2.
__global__ void __launch_bounds__(1024) k_hac(
        float* __restrict__ dist, const float* __restrict__ wsym,
        const float* __restrict__ values_g, const int* __restrict__ indices_g,
        int* __restrict__ labels_g, const u32* __restrict__ scal) {
    __shared__ __align__(16) float values_l[D];
    __shared__ int indices_l[D];
    __shared__ __align__(16) float newv_l[D];
    __shared__ float cs_l[D];
    __shared__ unsigned char dead_l[D];
    __shared__ int slot_l[D];   // leaf -> active slot id
    __shared__ int label_l[D];
    __shared__ double within_l[D];
    __shared__ double energy_l[D];
    __shared__ int rlist[2][D];
    __shared__ int nrec[2];
    __shared__ int listA[D], listB[D];
    __shared__ int nA_l[2], nB_l[2];
    __shared__ double crossP[16];  // per-wave pair-sum partials (big-merge path)
    __shared__ u64 wkeys[16];
    __shared__ int s_takeP, s_m1P, s_m2P, s_labP, s_bigP;
    __shared__ int s_pendSlot;
    __shared__ double s_pendW, s_pendE;

    const int t = threadIdx.x;
    const int lane = t & 63, wid = t >> 6;
    const float MAXD = __fmul_rn(dec_f(scal[1]), 1000.0f);
    const u32 MAXDb = __float_as_uint(MAXD);

    values_l[t] = values_g[t];
    indices_l[t] = indices_g[t];
    cs_l[t] = 1.0f;
    dead_l[t] = 0;
    slot_l[t] = t;
    label_l[t] = t;
    within_l[t] = 0.0;
    energy_l[t] = 0.0;
    if (t == 0) {
        s_takeP = 0; s_m1P = -1; s_m2P = -1; s_labP = 0; s_bigP = 0;
        s_pendSlot = -1;
        nrec[0] = 0; nrec[1] = 0;
        nA_l[0] = 0; nA_l[1] = 0; nB_l[0] = 0; nB_l[1] = 0;
    }
    __syncthreads();
    // boot: per-wave argmin over own 64 values -> wkeys (key = (value, row))
    {
        u64 key = ((u64)__float_as_uint(values_l[t]) << 32) | (u32)t;
        for (int o = 32; o; o >>= 1) {
            u64 k2 = __shfl_xor(key, o);
            if (k2 < key) key = k2;
        }
        if (lane == 0) wkeys[wid] = key;
    }
    __syncthreads();

    for (int it = 0; it < D - 1; ++it) {
        const int cb = it & 1, pb = cb ^ 1;

        // ================= P2 =================
        // finalize previous iteration's cut decision (big-merge path only):
        // all threads combine the per-wave pair-sum partials redundantly.
        int takeP;
        if (s_bigP) {
            double cab = 0.0;
#pragma unroll
            for (int w = 2; w < 16; ++w) cab += crossP[w];
            double merge_e = within_l[s_m1P] + within_l[s_m2P] + cab;
            double e_sum = energy_l[s_m1P] + energy_l[s_m2P];
            takeP = (merge_e >= e_sum) ? 1 : 0;
            if (t == 0) {  // stage updates; applied race-free by wave1-lane0 in P3
                s_pendSlot = s_m1P;
                s_pendW = merge_e;
                s_pendE = takeP ? merge_e : e_sum;
            }
        } else {
            takeP = s_takeP;
        }
        const int pm1 = s_m1P, plab = s_labP;

        // global argmin: combine the 16 wave keys (broadcast LDS reads)
        u64 best = wkeys[0];
#pragma unroll
        for (int w = 1; w < 16; ++w) {
            u64 k = wkeys[w];
            if (k < best) best = k;
        }
        const int m1 = (int)(best & 0xffffffffu);
        const int m2 = indices_l[m1];  // m2 > m1 always (upper-tri argmin)
        const float cs1 = cs_l[m1], cs2 = cs_l[m2];
        const float ncs = __fadd_rn(cs1, cs2);

        // freeze m2 early (own-thread write; alive read below sees it)
        if (t == m2) {
            dead_l[m2] = 1;
            values_l[m2] = MAXD;  // vmask freeze
            indices_l[m2] = 0;    // argmin of all-MAXD row
        }
        const bool alive = !dead_l[t];

        // issue the (only) 2 global row loads ASAP
        float d1, d2;
        if (alive) {
            d1 = dist[(size_t)m1 * D + t];
            d2 = dist[(size_t)m2 * D + t];
        }

        // deferred label apply + member-list build (pre-merge slots) + slot merge
        {
            int sl = slot_l[t];
            if (takeP && sl == pm1) label_l[t] = plab;
            bool inA = (sl == m1), inB = (sl == m2);
            u64 mA = __ballot(inA);
            if (mA) {  // wave-uniform
                int cnt = __popcll(mA);
                int basew = 0;
                if (lane == 0) basew = atomicAdd(&nA_l[cb], cnt);
                basew = __shfl(basew, 0);
                if (inA) listA[basew + __popcll(mA & ((1ull << lane) - 1))] = t;
            }
            u64 mB = __ballot(inB);
            if (mB) {
                int cnt = __popcll(mB);
                int basew = 0;
                if (lane == 0) basew = atomicAdd(&nB_l[cb], cnt);
                basew = __shfl(basew, 0);
                if (inB) listB[basew + __popcll(mB & ((1ull << lane) - 1))] = t;
            }
            if (inB) slot_l[t] = m1;  // merge membership
        }

        // merged distances
        float nv = MAXD;
        bool do_st = false;
        if (alive && t != m1) {
            nv = __fdiv_rn(__fadd_rn(__fmul_rn(d1, cs1), __fmul_rn(d2, cs2)), ncs);
            do_st = true;
        }
        newv_l[t] = nv;  // MAXD for dead/m1/m2 -> wave1 scan needs no dead mask

        // incremental row-min maintenance (thread t == row t)
        {
            float v = values_l[t];
            if (t == m1) {
                values_l[t] = MAXD;  // transient; wave1 recomputes from newv_l
            } else if (alive && v < MAXD) {
                int idx = indices_l[t];
                if (idx == m2) {
                    rlist[cb][atomicAdd(&nrec[cb], 1)] = t;
                    values_l[t] = MAXD;
                } else if (idx == m1) {  // implies t < m1
                    if (nv <= v) values_l[t] = nv;  // lowest-index tie preserved
                    else {
                        rlist[cb][atomicAdd(&nrec[cb], 1)] = t;
                        values_l[t] = MAXD;
                    }
                } else if (t < m1) {  // col m1 got nv in row t
                    if (nv < v) { values_l[t] = nv; indices_l[t] = m1; }
                    else if (nv == v && m1 < idx) indices_l[t] = m1;  // jnp.argmin tie-break
                }
            }
        }
        __syncthreads();  // B2

        // ================= P3 =================
        // dist stores at top: their drain overlaps the scans below
        if (do_st) {
            dist[(size_t)m1 * D + t] = nv;  // row m1 (coalesced)
            dist[(size_t)t * D + m1] = nv;  // col m1 (scattered)
        }
        if (t == m1) cs_l[m1] = ncs;  // nobody reads cs_l in P3
        const int n = nrec[cb];
        const int nA = nA_l[cb], nB = nB_l[cb];
        const int nP = nA * nB;
        const bool big = nP > 4096;
        if (t == 0) { nrec[pb] = 0; nA_l[pb] = 0; nB_l[pb] = 0; }

        u64 wkey = ~0ull;
        if (wid == 0) {
            // full argmin scan of values_l (transient-MAXD rows' true keys come
            // from wave1 / rescan waves — min-combine is exact)
            const float4* v4 = (const float4*)values_l;
            u64 bb = ~0ull;
#pragma unroll
            for (int c = 0; c < 4; ++c) {
                int fi = lane + 64 * c;
                float4 q = v4[fi];
                int b = fi << 2;
                u64 k;
                k = ((u64)__float_as_uint(q.x) << 32) | (u32)(b + 0); if (k < bb) bb = k;
                k = ((u64)__float_as_uint(q.y) << 32) | (u32)(b + 1); if (k < bb) bb = k;
                k = ((u64)__float_as_uint(q.z) << 32) | (u32)(b + 2); if (k < bb) bb = k;
                k = ((u64)__float_as_uint(q.w) << 32) | (u32)(b + 3); if (k < bb) bb = k;
            }
            for (int o = 32; o; o >>= 1) {
                u64 k2 = __shfl_xor(bb, o);
                if (k2 < bb) bb = k2;
            }
            wkey = bb;
        } else if (wid == 1) {
            // apply pending within/energy updates from a previous big merge
            // (only wave1-lane0 ever touches within_l/energy_l in P3 -> race-free)
            if (lane == 0 && s_pendSlot >= 0) {
                within_l[s_pendSlot] = s_pendW;
                energy_l[s_pendSlot] = s_pendE;
                s_pendSlot = -1;
            }
            // row m1's new min from LDS newv_l (dead cols are MAXD by construction)
            u64 bb = ((u64)MAXDb << 32);  // (MAXD, col 0)
            const float4* nv4 = (const float4*)newv_l;
            for (int c = lane; c < D / 4; c += 64) {
                float4 q = nv4[c];
                int j0 = c << 2;
#pragma unroll
                for (int e = 0; e < 4; ++e) {
                    int j = j0 + e;
                    float dv = (e == 0) ? q.x : (e == 1) ? q.y : (e == 2) ? q.z : q.w;
                    if (j > m1) {
                        u64 k = ((u64)__float_as_uint(dv) << 32) | (u32)j;
                        if (k < bb) bb = k;
                    }
                }
            }
            for (int o = 32; o; o >>= 1) {
                u64 k2 = __shfl_xor(bb, o);
                if (k2 < bb) bb = k2;
            }
            if (lane == 0) {
                values_l[m1] = __uint_as_float((u32)(bb >> 32));
                indices_l[m1] = (int)(bb & 0xffffffffu);
            }
            wkey = (bb & 0xffffffff00000000ull) | (u32)m1;  // key payload = ROW

            // cut decision: fast path sums all pairs here (wave1 only)
            if (!big) {
                double part = 0.0;
                for (int p = lane; p < nP; p += 64) {
                    int a = listA[p / nB];
                    int b = listB[p - (p / nB) * nB];
                    part += (double)wsym[(size_t)a * D + b];
                }
                for (int o = 32; o; o >>= 1) part += __shfl_xor(part, o);
                if (lane == 0) {
                    double merge_e = within_l[m1] + within_l[m2] + part;
                    double e_sum = energy_l[m1] + energy_l[m2];
                    int take = (merge_e >= e_sum) ? 1 : 0;
                    within_l[m1] = merge_e;
                    energy_l[m1] = take ? merge_e : e_sum;
                    s_takeP = take;
                }
            }
            if (lane == 0) {
                s_m1P = m1; s_m2P = m2; s_labP = D + it; s_bigP = big ? 1 : 0;
            }
        } else {
            // residual rescans (rows whose argmin retired/rose), one wave per row
            for (int q = wid - 2; q < n; q += 14) {
                const int r = rlist[cb][q];
                const float subst = newv_l[r];  // col-m1 value (store in flight)
                u64 bb = ((u64)MAXDb << 32);    // (MAXD, col 0)
                const float4* row4 = (const float4*)(dist + (size_t)r * D);
                for (int c = lane; c < D / 4; c += 64) {
                    float4 q4 = row4[c];
                    int j0 = c << 2;
#pragma unroll
                    for (int e = 0; e < 4; ++e) {
                        int j = j0 + e;
                        float dv = (e == 0) ? q4.x : (e == 1) ? q4.y : (e == 2) ? q4.z : q4.w;
                        if (j == m1) dv = subst;
                        if (j > r && !dead_l[j]) {
                            u64 k = ((u64)__float_as_uint(dv) << 32) | (u32)j;
                            if (k < bb) bb = k;
                        }
                    }
                }
                for (int o = 32; o; o >>= 1) {
                    u64 k2 = __shfl_xor(bb, o);
                    if (k2 < bb) bb = k2;
                }
                if (lane == 0) {
                    values_l[r] = __uint_as_float((u32)(bb >> 32));
                    indices_l[r] = (int)(bb & 0xffffffffu);
                }
                u64 rowkey = (bb & 0xffffffff00000000ull) | (u32)r;  // payload = ROW
                if (rowkey < wkey) wkey = rowkey;
            }
            // big-merge path: stripe the pair-sum across waves 2..15; the
            // decision is finalized at the top of the next P2.
            if (big) {
                double part = 0.0;
                for (int p = (wid - 2) * 64 + lane; p < nP; p += 14 * 64) {
                    int a = listA[p / nB];
                    int b = listB[p - (p / nB) * nB];
                    part += (double)wsym[(size_t)a * D + b];
                }
                for (int o = 32; o; o >>= 1) part += __shfl_xor(part, o);
                if (lane == 0) crossP[wid] = part;
            }
        }
        if (lane == 0) wkeys[wid] = wkey;
        __syncthreads();  // B3
    }

    // finalize the last iteration's cut (it may be on the big path), then emit
    {
        int takeF;
        if (s_bigP) {
            double cab = 0.0;
#pragma unroll
            for (int w = 2; w < 16; ++w) cab += crossP[w];
            double merge_e = within_l[s_m1P] + within_l[s_m2P] + cab;
            double e_sum = energy_l[s_m1P] + energy_l[s_m2P];
            takeF = (merge_e >= e_sum) ? 1 : 0;
        } else {
            takeF = s_takeP;
        }
        int lab = label_l[t];
        if (takeF && slot_l[t] == s_m1P) lab = s_labP;
        labels_g[t] = lab;
    }
}

// ---------- kernel D: R[a][b] = (a==b) || (label[a]==label[b]) ----------
__global__ void k_out(const int* __restrict__ labels, float* __restrict__ out) {
    int idx = blockIdx.x * blockDim.x + threadIdx.x;
    if (idx >= D * D) return;
    int i = idx >> 10, j = idx & (D - 1);
    out[idx] = (i == j || labels[i] == labels[j]) ? 1.0f : 0.0f;
}

extern "C" void kernel_launch(void* const* d_in, const int* in_sizes, int n_in,
                              void* d_out, int out_size, void* d_ws, size_t ws_size,
                              hipStream_t stream) {
    const float* X = (const float*)d_in[0];
    const float* W = (const float*)d_in[1];

    char* ws = (char*)d_ws;
    const size_t MAT_BYTES = (size_t)D * D * sizeof(float);  // 4 MiB each
    float* dist = (float*)ws;
    float* wsym = (float*)(ws + MAT_BYTES);
    float* values_g = (float*)(ws + 2 * MAT_BYTES);
    int* indices_g = (int*)(ws + 2 * MAT_BYTES + 4096);
    int* labels_g = (int*)(ws + 2 * MAT_BYTES + 8192);
    u32* scal = (u32*)(ws + 2 * MAT_BYTES + 12288);

    hipMemsetAsync(scal, 0, 2 * sizeof(u32), stream);
    k_maxred<<<256, 256, 0, stream>>>(X, scal);
    k_init<<<(D * D) / 256, 256, 0, stream>>>(X, W, dist, wsym, scal);
    k_rowmin<<<D, 64, 0, stream>>>(dist, values_g, indices_g, scal);
    k_hac<<<1, 1024, 0, stream>>>(dist, wsym, values_g, indices_g, labels_g, scal);
    k_out<<<(D * D) / 256, 256, 0, stream>>>(labels_g, (float*)d_out);
}

// Round 8
// 3488.683 us; speedup vs baseline: 1.3185x; 1.3185x over previous
//
#include <hip/hip_runtime.h>
#include <stdint.h>

#define D 1024

typedef unsigned long long u64;
typedef unsigned int u32;

// ---------- monotonic float<->uint mapping for atomic max ----------
__device__ __forceinline__ u32 enc_f(float f) {
    u32 b = __float_as_uint(f);
    return (b & 0x80000000u) ? ~b : (b | 0x80000000u);
}
__device__ __forceinline__ float dec_f(u32 u) {
    u32 b = (u & 0x80000000u) ? (u ^ 0x80000000u) : ~u;
    return __uint_as_float(b);
}

// ---------- kernel A: max(X), max|X| ----------
__global__ void k_maxred(const float* __restrict__ X, u32* scal) {
    float mx = -INFINITY, ma = 0.f;
    int stride = gridDim.x * blockDim.x;
    for (int i = blockIdx.x * blockDim.x + threadIdx.x; i < D * D; i += stride) {
        float v = X[i];
        mx = fmaxf(mx, v);
        ma = fmaxf(ma, fabsf(v));
    }
    for (int o = 32; o; o >>= 1) {
        mx = fmaxf(mx, __shfl_xor(mx, o));
        ma = fmaxf(ma, __shfl_xor(ma, o));
    }
    if ((threadIdx.x & 63) == 0) {
        atomicMax(&scal[0], enc_f(mx));  // max_sim
        atomicMax(&scal[1], enc_f(ma));  // max|X|
    }
}

// ---------- kernel B: init dist (f32) and cross (f32) matrices ----------
__global__ void k_init(const float* __restrict__ X, const float* __restrict__ W,
                       float* __restrict__ dist, float* __restrict__ cross,
                       const u32* __restrict__ scal) {
    int idx = blockIdx.x * blockDim.x + threadIdx.x;
    if (idx >= D * D) return;
    float max_sim = dec_f(scal[0]);
    float MAXD = __fmul_rn(dec_f(scal[1]), 1000.0f);
    int i = idx >> 10, j = idx & (D - 1);
    float x = X[idx];
    // X is bitwise symmetric (0.5*(A+A^T)), so this matches max_sim - X[min][max]
    dist[idx] = (i == j) ? MAXD : __fsub_rn(max_sim, x);
    cross[idx] = (i == j) ? 0.0f : (W[idx] + W[j * D + i]);  // one addend is exactly 0
}

// ---------- kernel B2: initial per-row (min,argmin) over upper triangle ----------
__global__ void k_rowmin(const float* __restrict__ dist, float* __restrict__ values_g,
                         int* __restrict__ indices_g, const u32* __restrict__ scal) {
    int r = blockIdx.x;
    int lane = threadIdx.x;  // 64 threads = 1 wave
    float MAXD = __fmul_rn(dec_f(scal[1]), 1000.0f);
    u64 best = ((u64)__float_as_uint(MAXD) << 32);  // (MAXD, idx 0) like jnp.argmin on all-MAXD row
    const float* row = dist + (size_t)r * D;
    for (int j = lane; j < D; j += 64) {
        if (j > r) {
            u64 k = ((u64)__float_as_uint(row[j]) << 32) | (u32)j;
            if (k < best) best = k;
        }
    }
    for (int o = 32; o; o >>= 1) {
        u64 k2 = __shfl_xor(best, o);
        if (k2 < best) best = k2;
    }
    if (lane == 0) {
        values_g[r] = __uint_as_float((u32)(best >> 32));
        indices_g[r] = (int)(best & 0xffffffffu);
    }
}

// ---------- kernel C: persistent single-block HAC loop, 2 barriers/iter ----------
// Global argmin via one LDS u64 atomicMin: key = valbits<<32 | row<<10 | col.
// P2 opens with a single LDS read giving (m1, m2) -- no per-thread combine.
__global__ void __launch_bounds__(1024) k_hac(
        float* __restrict__ dist, float* __restrict__ cross,
        const float* __restrict__ values_g, const int* __restrict__ indices_g,
        int* __restrict__ labels_g, const u32* __restrict__ scal) {
    __shared__ __align__(16) float values_l[D];
    __shared__ float values_stage[D];   // P3 scan results (restored next P2)
    __shared__ int indices_l[D];
    __shared__ __align__(16) float newv_l[D];
    __shared__ float cs_l[D];
    __shared__ unsigned char dead_l[D];
    __shared__ unsigned char marked_l[D];  // row staged in P3 -> restore next P2
    __shared__ int slot_l[D];   // leaf -> active slot id
    __shared__ int label_l[D];
    __shared__ double within_l[D];
    __shared__ double energy_l[D];
    __shared__ int rlist[2][D];
    __shared__ int nrec[2];
    __shared__ u64 s_best[2];   // double-buffered global-argmin accumulator
    __shared__ float s_cross12;
    __shared__ int s_takeP, s_m1P, s_labP;  // deferred cut (applied next iter)

    const int t = threadIdx.x;
    const int lane = t & 63, wid = t >> 6;
    const float MAXD = __fmul_rn(dec_f(scal[1]), 1000.0f);
    const u32 MAXDb = __float_as_uint(MAXD);

    values_l[t] = values_g[t];
    indices_l[t] = indices_g[t];
    cs_l[t] = 1.0f;
    dead_l[t] = 0;
    marked_l[t] = 0;
    slot_l[t] = t;
    label_l[t] = t;
    within_l[t] = 0.0;
    energy_l[t] = 0.0;
    if (t == 0) {
        s_takeP = 0; s_m1P = -1; s_labP = 0;
        nrec[0] = 0; nrec[1] = 0;
        s_best[0] = ~0ull; s_best[1] = ~0ull;
    }
    __syncthreads();
    // boot publish: per-wave reduce over own 64 rows -> atomicMin into s_best[0]
    {
        u64 key = ((u64)__float_as_uint(values_l[t]) << 32) | ((u32)t << 10) |
                  (u32)indices_l[t];
        for (int o = 32; o; o >>= 1) {
            u64 k2 = __shfl_xor(key, o);
            if (k2 < key) key = k2;
        }
        if (lane == 0) atomicMin(&s_best[0], key);
    }
    __syncthreads();

    for (int it = 0; it < D - 1; ++it) {
        const int cb = it & 1, pb = cb ^ 1;

        // ================= P2 =================
        const u64 bk = s_best[cb];  // one LDS read -> m1 AND m2
        const int m1 = (int)((bk >> 10) & 1023);
        const int m2 = (int)(bk & 1023);
        const float cs1 = cs_l[m1], cs2 = cs_l[m2];
        const float ncs = __fadd_rn(cs1, cs2);
        const int pm1 = s_m1P;
        if (t == 0) s_best[pb] = ~0ull;  // reset for this iter's publishers

        // restore staged P3 results, then freeze m2 (own-thread writes only)
        if (marked_l[t]) { values_l[t] = values_stage[t]; marked_l[t] = 0; }
        if (t == m2) {
            dead_l[m2] = 1;
            values_l[m2] = MAXD;  // vmask freeze
            indices_l[m2] = 0;    // argmin of all-MAXD row
        }
        const bool alive = !dead_l[t];

        // global row loads (cs reads above run in their shadow)
        float d1, d2, c1, c2;
        if (alive || t == m2) {
            d1 = dist[(size_t)m1 * D + t];
            d2 = dist[(size_t)m2 * D + t];
            c1 = cross[(size_t)m1 * D + t];
            c2 = cross[(size_t)m2 * D + t];
        }

        // deferred label apply (prev iter's cut), then slot merge
        {
            int sl = slot_l[t];
            if (s_takeP && sl == pm1) label_l[t] = s_labP;
            if (sl == m2) slot_l[t] = m1;
        }

        float nv = MAXD, ncx = 0.0f;
        bool do_st = false;
        {
            if (t == m2) s_cross12 = c1;  // old cross(m1,m2), consumed post-B2
            if (alive && t != m1) {
                nv = __fdiv_rn(__fadd_rn(__fmul_rn(d1, cs1), __fmul_rn(d2, cs2)), ncs);
                ncx = c1 + c2;
                dist[(size_t)m1 * D + t] = nv;    // row m1 (coalesced)
                cross[(size_t)m1 * D + t] = ncx;
                do_st = true;                     // col stores deferred to P3
            }
            newv_l[t] = nv;  // MAXD-fill: wave1 scan needs no dead mask
        }
        // incremental row-min maintenance (thread t == row t)
        {
            float v = values_l[t];
            if (t == m1) {
                values_l[t] = MAXD;  // transient; wave1 stages the new min
                marked_l[t] = 1;
            } else if (alive && v < MAXD) {
                int idx = indices_l[t];
                if (idx == m2) {
                    rlist[cb][atomicAdd(&nrec[cb], 1)] = t;
                    values_l[t] = MAXD;
                    marked_l[t] = 1;
                } else if (idx == m1) {  // implies t < m1
                    if (nv <= v) values_l[t] = nv;  // lowest-index tie preserved
                    else {
                        rlist[cb][atomicAdd(&nrec[cb], 1)] = t;
                        values_l[t] = MAXD;
                        marked_l[t] = 1;
                    }
                } else if (t < m1) {  // col m1 got nv in row t
                    if (nv < v) { values_l[t] = nv; indices_l[t] = m1; }
                    else if (nv == v && m1 < idx) indices_l[t] = m1;  // jnp.argmin tie-break
                }
            }
        }
        __syncthreads();  // B2

        // ================= P3 =================
        // scattered col stores first: their drain overlaps the scans below
        if (do_st) {
            dist[(size_t)t * D + m1] = nv;
            cross[(size_t)t * D + m1] = ncx;
        }
        if (t == m1) cs_l[m1] = ncs;  // nobody reads cs_l[m1] in P3
        const int n = nrec[cb];
        if (t == 0) nrec[pb] = 0;

        if (wid == 0) {
            if (lane == 0) {
                // cut decision (f64 accumulators)
                double merge_e = within_l[m1] + within_l[m2] + (double)s_cross12;
                double e_sum = energy_l[m1] + energy_l[m2];
                int take = (merge_e >= e_sum) ? 1 : 0;
                within_l[m1] = merge_e;
                energy_l[m1] = take ? merge_e : e_sum;
                s_takeP = take;
                s_m1P = m1;
                s_labP = D + it;
            }
            // full argmin scan of values_l (marked rows are MAXD and stable;
            // their true keys come from wave1/rescan publishers)
            const float4* v4 = (const float4*)values_l;
            u64 bb = ~0ull;  // (val<<32)|row during reduce
#pragma unroll
            for (int c = 0; c < 4; ++c) {
                int fi = lane + 64 * c;
                float4 q = v4[fi];
                int b = fi << 2;
                u64 k;
                k = ((u64)__float_as_uint(q.x) << 32) | (u32)(b + 0); if (k < bb) bb = k;
                k = ((u64)__float_as_uint(q.y) << 32) | (u32)(b + 1); if (k < bb) bb = k;
                k = ((u64)__float_as_uint(q.z) << 32) | (u32)(b + 2); if (k < bb) bb = k;
                k = ((u64)__float_as_uint(q.w) << 32) | (u32)(b + 3); if (k < bb) bb = k;
            }
            for (int o = 32; o; o >>= 1) {
                u64 k2 = __shfl_xor(bb, o);
                if (k2 < bb) bb = k2;
            }
            if (lane == 0) {
                int r = (int)(bb & 1023);
                int idx = indices_l[r];  // r is unmarked -> stable during P3
                atomicMin(&s_best[pb],
                          (bb & 0xffffffff00000000ull) | ((u32)r << 10) | (u32)idx);
            }
        } else if (wid == 1) {
            // row m1's new min from LDS newv_l (dead cols are MAXD by construction)
            u64 bb = ((u64)MAXDb << 32);  // (val<<32)|col
            const float4* nv4 = (const float4*)newv_l;
            for (int c = lane; c < D / 4; c += 64) {
                float4 q = nv4[c];
                int j0 = c << 2;
#pragma unroll
                for (int e = 0; e < 4; ++e) {
                    int j = j0 + e;
                    float dv = (e == 0) ? q.x : (e == 1) ? q.y : (e == 2) ? q.z : q.w;
                    if (j > m1) {
                        u64 k = ((u64)__float_as_uint(dv) << 32) | (u32)j;
                        if (k < bb) bb = k;
                    }
                }
            }
            for (int o = 32; o; o >>= 1) {
                u64 k2 = __shfl_xor(bb, o);
                if (k2 < bb) bb = k2;
            }
            if (lane == 0) {
                values_stage[m1] = __uint_as_float((u32)(bb >> 32));
                indices_l[m1] = (int)(bb & 0xffffffffu);
                atomicMin(&s_best[pb],
                          (bb & 0xffffffff00000000ull) | ((u32)m1 << 10) | (bb & 1023));
            }
        } else {
            // residual rescans (argmin retired/rose), one wave per row
            for (int q = wid - 2; q < n; q += 14) {
                const int r = rlist[cb][q];
                const float subst = newv_l[r];  // col-m1 value (store in flight)
                u64 bb = ((u64)MAXDb << 32);    // (val<<32)|col
                const float4* row4 = (const float4*)(dist + (size_t)r * D);
                for (int c = lane; c < D / 4; c += 64) {
                    float4 q4 = row4[c];
                    int j0 = c << 2;
#pragma unroll
                    for (int e = 0; e < 4; ++e) {
                        int j = j0 + e;
                        float dv = (e == 0) ? q4.x : (e == 1) ? q4.y : (e == 2) ? q4.z : q4.w;
                        if (j == m1) dv = subst;
                        if (j > r && !dead_l[j]) {
                            u64 k = ((u64)__float_as_uint(dv) << 32) | (u32)j;
                            if (k < bb) bb = k;
                        }
                    }
                }
                for (int o = 32; o; o >>= 1) {
                    u64 k2 = __shfl_xor(bb, o);
                    if (k2 < bb) bb = k2;
                }
                if (lane == 0) {
                    values_stage[r] = __uint_as_float((u32)(bb >> 32));
                    indices_l[r] = (int)(bb & 0xffffffffu);
                    atomicMin(&s_best[pb],
                              (bb & 0xffffffff00000000ull) | ((u32)r << 10) | (bb & 1023));
                }
            }
        }
        __syncthreads();  // B3
    }

    // apply the final iteration's deferred cut, then emit labels
    {
        int lab = label_l[t];
        if (s_takeP && slot_l[t] == s_m1P) lab = s_labP;
        labels_g[t] = lab;
    }
}

// ---------- kernel D: R[a][b] = (a==b) || (label[a]==label[b]) ----------
__global__ void k_out(const int* __restrict__ labels, float* __restrict__ out) {
    int idx = blockIdx.x * blockDim.x + threadIdx.x;
    if (idx >= D * D) return;
    int i = idx >> 10, j = idx & (D - 1);
    out[idx] = (i == j || labels[i] == labels[j]) ? 1.0f : 0.0f;
}

extern "C" void kernel_launch(void* const* d_in, const int* in_sizes, int n_in,
                              void* d_out, int out_size, void* d_ws, size_t ws_size,
                              hipStream_t stream) {
    const float* X = (const float*)d_in[0];
    const float* W = (const float*)d_in[1];

    char* ws = (char*)d_ws;
    const size_t MAT_BYTES = (size_t)D * D * sizeof(float);  // 4 MiB each
    float* dist = (float*)ws;
    float* cross = (float*)(ws + MAT_BYTES);
    float* values_g = (float*)(ws + 2 * MAT_BYTES);
    int* indices_g = (int*)(ws + 2 * MAT_BYTES + 4096);
    int* labels_g = (int*)(ws + 2 * MAT_BYTES + 8192);
    u32* scal = (u32*)(ws + 2 * MAT_BYTES + 12288);

    hipMemsetAsync(scal, 0, 2 * sizeof(u32), stream);
    k_maxred<<<256, 256, 0, stream>>>(X, scal);
    k_init<<<(D * D) / 256, 256, 0, stream>>>(X, W, dist, cross, scal);
    k_rowmin<<<D, 64, 0, stream>>>(dist, values_g, indices_g, scal);
    k_hac<<<1, 1024, 0, stream>>>(dist, cross, values_g, indices_g, labels_g, scal);
    k_out<<<(D * D) / 256, 256, 0, stream>>>(labels_g, (float*)d_out);
}